// Round 3
// baseline (349.226 us; speedup 1.0000x reference)
//
#include <hip/hip_runtime.h>

#define B_ 256
#define T_ 1024
#define V_ 5000
#define D_ 100
#define H_ 64
#define C_ 2

typedef float f32x4 __attribute__((ext_vector_type(4)));

// ---------------------------------------------------------------------------
// Kernel 1: EW[v][h] = 2*(sum_d E[v][d] * W[d][h] + b[h])
// Pre-doubled (exact in fp32) so the RNN's tanh needs e^{x2} with no 2*x mul.
// ---------------------------------------------------------------------------
__global__ __launch_bounds__(256) void ew_kernel(const float* __restrict__ E,
                                                 const float* __restrict__ W,
                                                 const float* __restrict__ bias,
                                                 float* __restrict__ EW) {
    int idx = blockIdx.x * 256 + threadIdx.x;   // 0 .. V_*H_
    if (idx >= V_ * H_) return;
    int h = idx & (H_ - 1);
    int v = idx >> 6;
    float acc = bias[h];
    const float* Erow = E + v * D_;
    #pragma unroll 4
    for (int d = 0; d < D_; ++d) {
        acc = fmaf(Erow[d], W[d * H_ + h], acc);
    }
    EW[idx] = 2.0f * acc;    // x2 fold: exact scaling, bit-identical tanh
}

// ---------------------------------------------------------------------------
// Kernel 2: per-batch RNN. One wave per batch element.
// R7: two coupled fixes to the 650-cyc/step invariant of R4-R6:
//  (1) U pinned in 64 VGPRs via ONE asm with all 16 float4 quads as
//      simultaneous operands (R6's per-element pins allowed one-at-a-time
//      load->pin->spill; VGPR_Count=40 proved it). A second 16-operand pin
//      INSIDE the T-loop makes spilling strictly unprofitable.
//  (2) h broadcast via LDS instead of 64 v_readlane: lane j writes h to
//      sh_h[j] (ds_write_b32), all lanes re-read it as 16 uniform-address
//      ds_read_b128 (same-address = HW broadcast, no conflict; DS pipe is
//      in-order per wave, single wave => no barrier). Kills 64 readlanes +
//      their VALU->SGPR hazard bubbles per step.
// Step issue budget: 1 ds_write + 16 ds_read_b128 + 64 v_fmac + ~10 tail
// ~= 182 cyc + LDS roundtrip on the serial chain => ~230-300 cyc/step.
// Kept: padded sh_tok (no tail guard), 2-step EW prefetch, clampless tanh
// hn = 1 - 2*rcp(e^{x2}+1)  (x2 pre-doubled; inf->1, 0->-1, no NaN).
// ---------------------------------------------------------------------------
__global__ __launch_bounds__(64, 1) void rnn_kernel(const int* __restrict__ tokens,
                                                    const float* __restrict__ EW,
                                                    const float* __restrict__ U,
                                                    const float* __restrict__ Wd,
                                                    const float* __restrict__ bd,
                                                    float* __restrict__ out) {
    const int b = blockIdx.x;     // batch element
    const int j = threadIdx.x;    // 0..63 : hidden unit

    __shared__ int   sh_tok[T_ + 2];   // 4 KB + pad (kills tail guard)
    __shared__ float sh_h[H_];         // h broadcast buffer (256 B)

    // --- 2*U column j -> 16 float4 (64 VGPRs). Coalesced across lanes. ---
    f32x4 uq[16];
    #pragma unroll
    for (int c = 0; c < 16; ++c) {
        uq[c][0] = 2.0f * U[(4 * c + 0) * H_ + j];
        uq[c][1] = 2.0f * U[(4 * c + 1) * H_ + j];
        uq[c][2] = 2.0f * U[(4 * c + 2) * H_ + j];
        uq[c][3] = 2.0f * U[(4 * c + 3) * H_ + j];
    }
    // SINGLE pin: all 64 values must be live in VGPRs at once.
    asm volatile("" : "+v"(uq[0]), "+v"(uq[1]), "+v"(uq[2]), "+v"(uq[3]),
                      "+v"(uq[4]), "+v"(uq[5]), "+v"(uq[6]), "+v"(uq[7]),
                      "+v"(uq[8]), "+v"(uq[9]), "+v"(uq[10]), "+v"(uq[11]),
                      "+v"(uq[12]), "+v"(uq[13]), "+v"(uq[14]), "+v"(uq[15]));

    const int* tok = tokens + b * T_;
    #pragma unroll
    for (int k = 0; k < T_ / H_; ++k) {
        sh_tok[k * H_ + j] = tok[k * H_ + j];    // coalesced
    }
    if (j < 2) sh_tok[T_ + j] = 0;               // pad
    __syncthreads();

    float h = 0.f;
    float pooled = 0.f;

    // 2-step-deep xw prefetch pipeline (covers L2 latency of EW gather)
    int2 tkA = *(const int2*)&sh_tok[0];
    float xw0 = EW[tkA.x * H_ + j];
    float xw1 = EW[tkA.y * H_ + j];

    // one recurrence step: LDS h-broadcast, register U, clampless tanh
    #define RNN_STEP(tokv, xwv)                                          \
    {                                                                    \
        sh_h[j] = h;                                                     \
        float a0 = (xwv), a1 = 0.f, a2 = 0.f, a3 = 0.f;                  \
        _Pragma("unroll")                                                \
        for (int c = 0; c < 16; ++c) {                                   \
            f32x4 hv = *(const f32x4*)&sh_h[4 * c];                      \
            a0 = fmaf(hv[0], uq[c][0], a0);                              \
            a1 = fmaf(hv[1], uq[c][1], a1);                              \
            a2 = fmaf(hv[2], uq[c][2], a2);                              \
            a3 = fmaf(hv[3], uq[c][3], a3);                              \
        }                                                                \
        float x2 = (a0 + a1) + (a2 + a3);                                \
        float e = __expf(x2);                                            \
        float r = __builtin_amdgcn_rcpf(e + 1.f);                        \
        float hn = fmaf(-2.f, r, 1.f);                                   \
        h = ((tokv) != 0) ? hn : h;                                      \
        pooled += h;                                                     \
    }

    for (int t = 0; t < T_; t += 2) {
        // in-loop pin: uq must be in VGPRs here every iteration, so any
        // spill would force an in-loop reload -- allocator keeps them.
        asm volatile("" :: "v"(uq[0]), "v"(uq[1]), "v"(uq[2]), "v"(uq[3]),
                           "v"(uq[4]), "v"(uq[5]), "v"(uq[6]), "v"(uq[7]),
                           "v"(uq[8]), "v"(uq[9]), "v"(uq[10]), "v"(uq[11]),
                           "v"(uq[12]), "v"(uq[13]), "v"(uq[14]), "v"(uq[15]));

        // prefetch steps t+2, t+3 (pad makes the tail read safe: EW[0])
        int2 tkB = *(const int2*)&sh_tok[t + 2];
        float xw2 = EW[tkB.x * H_ + j];
        float xw3 = EW[tkB.y * H_ + j];

        RNN_STEP(tkA.x, xw0);
        RNN_STEP(tkA.y, xw1);

        tkA = tkB;
        xw0 = xw2;
        xw1 = xw3;
    }
    #undef RNN_STEP

    // ---- epilogue: pooled mean -> dense(2) -> sigmoid ----
    float p = pooled * (1.0f / (float)T_);
    float v0 = p * Wd[j * C_ + 0];
    float v1 = p * Wd[j * C_ + 1];
    #pragma unroll
    for (int off = 32; off >= 1; off >>= 1) {
        v0 += __shfl_down(v0, off, 64);
        v1 += __shfl_down(v1, off, 64);
    }
    if (j == 0) {
        float l0 = v0 + bd[0];
        float l1 = v1 + bd[1];
        out[b * C_ + 0] = 1.f / (1.f + __expf(-l0));
        out[b * C_ + 1] = 1.f / (1.f + __expf(-l1));
    }
}

// ---------------------------------------------------------------------------
extern "C" void kernel_launch(void* const* d_in, const int* in_sizes, int n_in,
                              void* d_out, int out_size, void* d_ws, size_t ws_size,
                              hipStream_t stream) {
    const int*   tokens = (const int*)  d_in[0];  // [B,T] int32
    const float* E      = (const float*)d_in[1];  // [V,D]
    const float* W      = (const float*)d_in[2];  // [D,H]
    const float* U      = (const float*)d_in[3];  // [H,H]
    const float* bias   = (const float*)d_in[4];  // [H]
    const float* Wd     = (const float*)d_in[5];  // [H,C]
    const float* bd     = (const float*)d_in[6];  // [C]
    float* out = (float*)d_out;                   // [B,C]
    float* EW  = (float*)d_ws;                    // [V,H] scratch: 1.28 MB

    ew_kernel<<<(V_ * H_ + 255) / 256, 256, 0, stream>>>(E, W, bias, EW);
    rnn_kernel<<<B_, H_, 0, stream>>>(tokens, EW, U, Wd, bd, out);
}